// Round 10
// baseline (146.865 us; speedup 1.0000x reference)
//
#include <hip/hip_runtime.h>
#include <stdint.h>
#include <stddef.h>

typedef __attribute__((ext_vector_type(8))) short short8;
typedef __attribute__((ext_vector_type(4))) float f32x4;
typedef __attribute__((ext_vector_type(16))) float f32x16;
typedef __attribute__((ext_vector_type(4))) unsigned int uint4v;

#define MFMA16(a, b, c) __builtin_amdgcn_mfma_f32_16x16x32_bf16((a), (b), (c), 0, 0, 0)
#define MFMA32(a, b, c) __builtin_amdgcn_mfma_f32_32x32x16_bf16((a), (b), (c), 0, 0, 0)

__device__ __forceinline__ unsigned short f2bf(float f) {
  unsigned int u = __builtin_bit_cast(unsigned int, f);
  u += 0x7fffu + ((u >> 16) & 1u);
  return (unsigned short)(u >> 16);
}

// validated integer RNE pack (round 5) — cold paths
__device__ __forceinline__ unsigned int pk2(float lo, float hi) {
  return (unsigned int)f2bf(lo) | ((unsigned int)f2bf(hi) << 16);
}

// fast round-nearest pack — hot path (positive finite values only)
__device__ __forceinline__ unsigned int pk2rn(float lo, float hi) {
  unsigned int a = __builtin_bit_cast(unsigned int, lo) + 0x8000u;
  unsigned int b = __builtin_bit_cast(unsigned int, hi) + 0x8000u;
  return (b & 0xFFFF0000u) | (a >> 16);
}

__device__ __forceinline__ short8 mk8(const unsigned short* p) {
  return *(const short8*)p;
}

// cross-half (lane^32) reductions via validated __shfl_xor primitive
__device__ __forceinline__ float redmax32(float v) {
  return fmaxf(v, __shfl_xor(v, 32));
}
__device__ __forceinline__ float redsum32(float v) {
  return v + __shfl_xor(v, 32);
}

__device__ __forceinline__ f32x16 zero16() {
  f32x16 v;
#pragma unroll
  for (int i = 0; i < 16; ++i) v[i] = 0.f;
  return v;
}

// swizzled offset into a [rows][40]-half LDS tile holding 32 data cols.
__device__ __forceinline__ int swz40(int row, int c) {
  return row * 40 + ((((c >> 3) ^ (row >> 3)) & 3) << 3) + (c & 7);
}

// ---------------- kernel 0: cast weights to bf16 ----------------
__global__ __launch_bounds__(256) void k_prep(const float* __restrict__ wq,
                                              const float* __restrict__ wo,
                                              unsigned short* __restrict__ wq_bf,
                                              unsigned short* __restrict__ wo_bf) {
  int i = blockIdx.x * 256 + threadIdx.x;
  if (i < 98304) wq_bf[i] = f2bf(wq[i]);
  if (i < 32768) wo_bf[i] = f2bf(wo[i]);
}

// ---------------- kernel 1: fused RMSNorm + QKV GEMM ----------------
// Output layouts:
//   Q, K: [bh][p][d]   buf + (bh*4096 + p)*32 + d
//   V:    [bh][d][p']  p' = sigma(p) within each 16-block (swap bits 2,3)
__global__ __launch_bounds__(256) void k_qkv(const float* __restrict__ x,
                                             const float* __restrict__ g,
                                             const unsigned short* __restrict__ wq_bf,
                                             unsigned short* __restrict__ qbuf,
                                             unsigned short* __restrict__ kbuf,
                                             unsigned short* __restrict__ vbuf) {
  int bid = blockIdx.x;            // 768 = 4b * 6ot * 32pt
  int b = bid / 192;
  int rem = bid % 192;
  int ot = rem / 32;
  int pt = rem % 32;
  int o0 = ot * 64, p0 = pt * 128;

  __shared__ unsigned short xnT[128 * 40];
  __shared__ float sq[2][128];
  __shared__ float rl[128];

  int t = threadIdx.x;
  int lane = t & 63, w = t >> 6;
  int lr = lane & 15, lg = lane >> 4;
  int pl = t & 127, ch = t >> 7;

  const float* xb = x + (size_t)b * 256 * 4096;
  const unsigned short* wqrow = wq_bf + (size_t)(o0 + w * 16 + lr) * 256;

  f32x4 acc[8];
  f32x4 z = {0.f, 0.f, 0.f, 0.f};
#pragma unroll
  for (int i = 0; i < 8; ++i) acc[i] = z;
  float sacc = 0.f;

  for (int c0 = 0; c0 < 256; c0 += 32) {
    __syncthreads();
#pragma unroll
    for (int i = 0; i < 8; ++i) {
      int c = ch * 16 + i * 2;
      float v0 = xb[(size_t)(c0 + c) * 4096 + p0 + pl];
      float v1 = xb[(size_t)(c0 + c + 1) * 4096 + p0 + pl];
      sacc += v0 * v0 + v1 * v1;
      *(unsigned int*)&xnT[swz40(pl, c)] = pk2(v0 * g[c0 + c], v1 * g[c0 + c + 1]);
    }
    __syncthreads();
    short8 af = mk8(wqrow + c0 + lg * 8);
#pragma unroll
    for (int pt16 = 0; pt16 < 8; ++pt16) {
      short8 bf = mk8(&xnT[swz40(pt16 * 16 + lr, lg * 8)]);
      acc[pt16] = MFMA16(af, bf, acc[pt16]);
    }
  }

  sq[ch][pl] = sacc;
  __syncthreads();
  if (t < 128) rl[t] = rsqrtf((sq[0][t] + sq[1][t]) * (1.0f / 256.0f) + 1e-12f);
  __syncthreads();

  int obase = o0 + w * 16 + lg * 4;          // multiple of 4
  if (obase < 256) {
    int isK = obase >= 128;
    int oh = obase - (isK ? 128 : 0);
    int h = oh >> 5, d0 = oh & 31;
    unsigned short* dst = (isK ? kbuf : qbuf) + ((size_t)(b * 4 + h) * 4096) * 32;
#pragma unroll
    for (int pt16 = 0; pt16 < 8; ++pt16) {
      int p = p0 + pt16 * 16 + lr;
      float rr = rl[pt16 * 16 + lr];
      unsigned int u0 = pk2(acc[pt16][0] * rr, acc[pt16][1] * rr);
      unsigned int u1 = pk2(acc[pt16][2] * rr, acc[pt16][3] * rr);
      uint2 uu = {u0, u1};
      *(uint2*)(dst + (size_t)p * 32 + d0) = uu;
    }
  } else {
    int oh = obase - 256;
    int h = oh >> 5, d0 = oh & 31;
    unsigned short* dst = vbuf + ((size_t)(b * 4 + h) * 32) * 4096;
    // sigma: swap bits 2 and 3 of the within-block index (involution)
    int sl = (lr & 3) | ((lr & 4) << 1) | ((lr & 8) >> 1);
#pragma unroll
    for (int pt16 = 0; pt16 < 8; ++pt16) {
      int pp = p0 + pt16 * 16 + sl;
      float rr = rl[pt16 * 16 + lr];
#pragma unroll
      for (int r = 0; r < 4; ++r)
        dst[(size_t)(d0 + r) * 4096 + pp] = f2bf(acc[pt16][r] * rr);
    }
  }
}

// ---------------- kernel 2: flash attention, KV-split x4 ----------------
// grid 2048 = 16 bh x 128 q-groups of 32 rows; 4 waves = 4 j-quarters (1024 j
// each) of the SAME q-group, merged via LDS at the end. 8192 waves total.
__device__ __forceinline__ void attn_tile(short8 kf0, short8 kf1, short8 vf0, short8 vf1,
                                          short8 qf0, short8 qf1,
                                          const f32x16& z16, float& m, float& ms,
                                          float& lsum, f32x16& oacc) {
  const float cexp = 0.25505654427102996f;  // 32^-0.5 * log2(e)
  f32x16 s = MFMA32(kf0, qf0, z16);
  s = MFMA32(kf1, qf1, s);

  // per-lane local max over 16 values (nested fmax -> v_max3)
  float a0 = fmaxf(fmaxf(s[0], s[1]), s[2]);
  float a1 = fmaxf(fmaxf(s[3], s[4]), s[5]);
  float a2 = fmaxf(fmaxf(s[6], s[7]), s[8]);
  float a3 = fmaxf(fmaxf(s[9], s[10]), s[11]);
  float a4 = fmaxf(fmaxf(s[12], s[13]), s[14]);
  float b0 = fmaxf(fmaxf(a0, a1), a2);
  float b1 = fmaxf(fmaxf(a3, a4), s[15]);
  float plmax = fmaxf(b0, b1);

  // defer-max: shared-ms update (with cross-half shuffle) only when needed.
  if (!__all(fmaf(plmax, cexp, -ms) <= 8.0f)) {
    float pmax = redmax32(plmax);           // keep ms identical across lane pair
    float mn = fmaxf(m, pmax);
    float fac = __builtin_amdgcn_exp2f((m - mn) * cexp);
    m = mn;
    ms = mn * cexp;
    lsum *= fac;
#pragma unroll
    for (int i = 0; i < 16; ++i) oacc[i] *= fac;
  }

  float p[16];
#pragma unroll
  for (int i = 0; i < 16; ++i) p[i] = __builtin_amdgcn_exp2f(fmaf(s[i], cexp, -ms));

  float s0 = ((p[0] + p[1]) + (p[2] + p[3])) + ((p[4] + p[5]) + (p[6] + p[7]));
  float s1 = ((p[8] + p[9]) + (p[10] + p[11])) + ((p[12] + p[13]) + (p[14] + p[15]));
  lsum += s0 + s1;

  // Own-lane B-fragments (fast RN pack); V stored sigma-permuted to match
  uint4v u0 = {pk2rn(p[0], p[1]), pk2rn(p[2], p[3]), pk2rn(p[4], p[5]), pk2rn(p[6], p[7])};
  uint4v u1 = {pk2rn(p[8], p[9]), pk2rn(p[10], p[11]), pk2rn(p[12], p[13]), pk2rn(p[14], p[15])};
  short8 pf0 = __builtin_bit_cast(short8, u0);
  short8 pf1 = __builtin_bit_cast(short8, u1);

  oacc = MFMA32(vf0, pf0, oacc);
  oacc = MFMA32(vf1, pf1, oacc);
}

__global__ __launch_bounds__(256, 4) void k_attn(const unsigned short* __restrict__ qbuf,
                                                 const unsigned short* __restrict__ kbuf,
                                                 const unsigned short* __restrict__ vbuf,
                                                 unsigned short* __restrict__ attno) {
  __shared__ float Ol[3][16][64];   // partner O partials (jq 1..3)
  __shared__ float Ml[3][2][64];    // partner m / lsum

  int bid = blockIdx.x;
  int wid = ((bid & 7) << 8) | (bid >> 3);   // XCD-contiguous (2048 % 8 == 0)
  int qg = wid & 127, bh = wid >> 7;
  int t = threadIdx.x, lane = t & 63, jq = t >> 6;
  int l31 = lane & 31, hi = lane >> 5;
  const float cexp = 0.25505654427102996f;

  const unsigned short* qgp = qbuf + (size_t)bh * 4096 * 32;
  const unsigned short* kg = kbuf + (size_t)bh * 4096 * 32;
  const unsigned short* vg = vbuf + (size_t)bh * 32 * 4096;

  int qrow = qg * 32 + l31;
  short8 qf0 = mk8(qgp + (size_t)qrow * 32 + hi * 8);
  short8 qf1 = mk8(qgp + (size_t)qrow * 32 + 16 + hi * 8);

  const f32x16 z16 = zero16();
  f32x16 oacc = zero16();
  float m = -1e30f, ms = -2.55e29f, lsum = 0.f;

  int jbase = jq * 1024;
  const unsigned short* kp = kg + (size_t)(jbase + l31) * 32 + hi * 8;
  const unsigned short* vp = vg + (size_t)l31 * 4096 + hi * 8 + jbase;

  short8 kf0a = mk8(kp), kf1a = mk8(kp + 16);
  short8 vf0a = mk8(vp), vf1a = mk8(vp + 16);
  kp += 32 * 32;
  vp += 32;
  short8 kf0b, kf1b, vf0b, vf1b;

  for (int it = 0; it < 16; ++it) {          // 16 iters x 64 j = 1024 j
    kf0b = mk8(kp);
    kf1b = mk8(kp + 16);
    vf0b = mk8(vp);
    vf1b = mk8(vp + 16);
    kp += 1024;
    vp += 32;
    attn_tile(kf0a, kf1a, vf0a, vf1a, qf0, qf1, z16, m, ms, lsum, oacc);

    kf0a = mk8(kp);                          // last iter: dead prefetch (mapped ws)
    kf1a = mk8(kp + 16);
    vf0a = mk8(vp);
    vf1a = mk8(vp + 16);
    kp += 1024;
    vp += 32;
    attn_tile(kf0b, kf1b, vf0b, vf1b, qf0, qf1, z16, m, ms, lsum, oacc);
  }

  lsum = redsum32(lsum);   // pair row-total for this j-quarter

  if (jq > 0) {
#pragma unroll
    for (int i = 0; i < 16; ++i) Ol[jq - 1][i][lane] = oacc[i];
    Ml[jq - 1][0][lane] = m;
    Ml[jq - 1][1][lane] = lsum;
  }
  __syncthreads();
  if (jq == 0) {
    float m1 = Ml[0][0][lane], l1 = Ml[0][1][lane];
    float m2 = Ml[1][0][lane], l2 = Ml[1][1][lane];
    float m3 = Ml[2][0][lane], l3 = Ml[2][1][lane];
    float M = fmaxf(fmaxf(m, m1), fmaxf(m2, m3));
    float f0 = __builtin_amdgcn_exp2f((m - M) * cexp);
    float f1 = __builtin_amdgcn_exp2f((m1 - M) * cexp);
    float f2 = __builtin_amdgcn_exp2f((m2 - M) * cexp);
    float f3 = __builtin_amdgcn_exp2f((m3 - M) * cexp);
    float rinv = 1.0f / (lsum * f0 + l1 * f1 + l2 * f2 + l3 * f3);
    f0 *= rinv;
    f1 *= rinv;
    f2 *= rinv;
    f3 *= rinv;

    int b = bh >> 2, h = bh & 3;
    unsigned short* ob = attno + ((size_t)b * 4096 + qrow) * 128 + h * 32;
#pragma unroll
    for (int r2 = 0; r2 < 8; ++r2) {
      int reg = r2 * 2;
      int dv = (reg & 3) + 8 * (reg >> 2) + 4 * hi;
      float v0 = oacc[reg] * f0 + Ol[0][reg][lane] * f1 + Ol[1][reg][lane] * f2 + Ol[2][reg][lane] * f3;
      float v1 = oacc[reg + 1] * f0 + Ol[0][reg + 1][lane] * f1 + Ol[1][reg + 1][lane] * f2 + Ol[2][reg + 1][lane] * f3;
      *(unsigned int*)(ob + dv) = pk2(v0, v1);
    }
  }
}

// ---------------- kernel 3: output projection + bias ----------------
__global__ __launch_bounds__(256) void k_out(const unsigned short* __restrict__ attno,
                                             const unsigned short* __restrict__ wo_bf,
                                             const float* __restrict__ bo,
                                             float* __restrict__ out) {
  int bid = blockIdx.x;
  int b = bid >> 6;
  int p0 = (bid & 63) * 64;
  int t = threadIdx.x, lane = t & 63, w = t >> 6;
  int lr = lane & 15, lg = lane >> 4;

  f32x4 z = {0.f, 0.f, 0.f, 0.f};
  f32x4 acc[4][4];
#pragma unroll
  for (int i = 0; i < 4; ++i)
#pragma unroll
    for (int j = 0; j < 4; ++j) acc[i][j] = z;

  for (int c0 = 0; c0 < 128; c0 += 32) {
    short8 bfr[4];
#pragma unroll
    for (int pt16 = 0; pt16 < 4; ++pt16)
      bfr[pt16] = mk8(attno + (size_t)(b * 4096 + p0 + pt16 * 16 + lr) * 128 + c0 + lg * 8);
#pragma unroll
    for (int ct = 0; ct < 4; ++ct) {
      short8 afr = mk8(wo_bf + (size_t)(w * 64 + ct * 16 + lr) * 128 + c0 + lg * 8);
#pragma unroll
      for (int pt16 = 0; pt16 < 4; ++pt16)
        acc[ct][pt16] = MFMA16(afr, bfr[pt16], acc[ct][pt16]);
    }
  }

#pragma unroll
  for (int ct = 0; ct < 4; ++ct) {
#pragma unroll
    for (int pt16 = 0; pt16 < 4; ++pt16) {
#pragma unroll
      for (int r = 0; r < 4; ++r) {
        int co = w * 64 + ct * 16 + lg * 4 + r;
        int p = p0 + pt16 * 16 + lr;
        out[((size_t)b * 256 + co) * 4096 + p] = acc[ct][pt16][r] + bo[co];
      }
    }
  }
}

extern "C" void kernel_launch(void* const* d_in, const int* in_sizes, int n_in,
                              void* d_out, int out_size, void* d_ws, size_t ws_size,
                              hipStream_t stream) {
  const float* x = (const float*)d_in[0];
  const float* g = (const float*)d_in[1];
  const float* wq = (const float*)d_in[2];
  const float* wo = (const float*)d_in[3];
  const float* bo = (const float*)d_in[4];
  float* out = (float*)d_out;

  char* ws = (char*)d_ws;
  unsigned short* wq_bf = (unsigned short*)(ws + 65536);     // 196608 B
  unsigned short* wo_bf = (unsigned short*)(ws + 262144);    // 65536 B
  unsigned short* qbuf = (unsigned short*)(ws + 327680);     // 4 MiB
  unsigned short* kbuf = (unsigned short*)(ws + 4521984);    // 4 MiB
  unsigned short* vbuf = (unsigned short*)(ws + 8716288);    // 4 MiB
  unsigned short* attno = (unsigned short*)(ws + 12910592);  // 4 MiB

  k_prep<<<dim3(384), dim3(256), 0, stream>>>(wq, wo, wq_bf, wo_bf);
  k_qkv<<<dim3(768), dim3(256), 0, stream>>>(x, g, wq_bf, qbuf, kbuf, vbuf);
  k_attn<<<dim3(2048), dim3(256), 0, stream>>>(qbuf, kbuf, vbuf, attno);
  k_out<<<dim3(256), dim3(256), 0, stream>>>(attno, wo_bf, bo, out);
}

// Round 11
// 119.770 us; speedup vs baseline: 1.2262x; 1.2262x over previous
//
#include <hip/hip_runtime.h>
#include <stdint.h>
#include <stddef.h>

typedef __attribute__((ext_vector_type(8))) short short8;
typedef __attribute__((ext_vector_type(4))) float f32x4;
typedef __attribute__((ext_vector_type(16))) float f32x16;
typedef __attribute__((ext_vector_type(4))) unsigned int uint4v;

#define MFMA16(a, b, c) __builtin_amdgcn_mfma_f32_16x16x32_bf16((a), (b), (c), 0, 0, 0)
#define MFMA32(a, b, c) __builtin_amdgcn_mfma_f32_32x32x16_bf16((a), (b), (c), 0, 0, 0)

__device__ __forceinline__ unsigned short f2bf(float f) {
  unsigned int u = __builtin_bit_cast(unsigned int, f);
  u += 0x7fffu + ((u >> 16) & 1u);
  return (unsigned short)(u >> 16);
}

// validated integer RNE pack (round 5) — cold paths
__device__ __forceinline__ unsigned int pk2(float lo, float hi) {
  return (unsigned int)f2bf(lo) | ((unsigned int)f2bf(hi) << 16);
}

// fast round-nearest pack — hot path (positive finite values only)
__device__ __forceinline__ unsigned int pk2rn(float lo, float hi) {
  unsigned int a = __builtin_bit_cast(unsigned int, lo) + 0x8000u;
  unsigned int b = __builtin_bit_cast(unsigned int, hi) + 0x8000u;
  return (b & 0xFFFF0000u) | (a >> 16);
}

__device__ __forceinline__ short8 mk8(const unsigned short* p) {
  return *(const short8*)p;
}

// cross-half (lane^32) reductions via validated __shfl_xor primitive
__device__ __forceinline__ float redmax32(float v) {
  return fmaxf(v, __shfl_xor(v, 32));
}
__device__ __forceinline__ float redsum32(float v) {
  return v + __shfl_xor(v, 32);
}

__device__ __forceinline__ f32x16 zero16() {
  f32x16 v;
#pragma unroll
  for (int i = 0; i < 16; ++i) v[i] = 0.f;
  return v;
}

// swizzled offset into a [rows][40]-half LDS tile holding 32 data cols.
__device__ __forceinline__ int swz40(int row, int c) {
  return row * 40 + ((((c >> 3) ^ (row >> 3)) & 3) << 3) + (c & 7);
}

// ---------------- kernel 0: cast weights to bf16 ----------------
__global__ __launch_bounds__(256) void k_prep(const float* __restrict__ wq,
                                              const float* __restrict__ wo,
                                              unsigned short* __restrict__ wq_bf,
                                              unsigned short* __restrict__ wo_bf) {
  int i = blockIdx.x * 256 + threadIdx.x;
  if (i < 98304) wq_bf[i] = f2bf(wq[i]);
  if (i < 32768) wo_bf[i] = f2bf(wo[i]);
}

// ---------------- kernel 1: fused RMSNorm + QKV GEMM ----------------
// Output layouts:
//   Q: [bh][p][d]                      (loaded once per wave in k_attn)
//   K: fragment-linear per (bh, jtile): [jtile][frag][lane][8]
//      lane = hi*32 + j31; frag f, slot i -> K[j = jtile*32+j31][d = f*16+hi*8+i]
//   V: fragment-linear per (bh, jtile): [jtile][frag][lane][8]
//      lane = hi*32 + d31; frag f, slot i -> V[d = d31][j* = jtile*32 + sigma-stored
//      position f*16+hi*8+i]  (sigma: swap bits 2,3 within 16-block, as r5)
__global__ __launch_bounds__(256) void k_qkv(const float* __restrict__ x,
                                             const float* __restrict__ g,
                                             const unsigned short* __restrict__ wq_bf,
                                             unsigned short* __restrict__ qbuf,
                                             unsigned short* __restrict__ kbuf,
                                             unsigned short* __restrict__ vbuf) {
  int bid = blockIdx.x;            // 768 = 4b * 6ot * 32pt
  int b = bid / 192;
  int rem = bid % 192;
  int ot = rem / 32;
  int pt = rem % 32;
  int o0 = ot * 64, p0 = pt * 128;

  __shared__ unsigned short xnT[128 * 40];
  __shared__ float sq[2][128];
  __shared__ float rl[128];

  int t = threadIdx.x;
  int lane = t & 63, w = t >> 6;
  int lr = lane & 15, lg = lane >> 4;
  int pl = t & 127, ch = t >> 7;

  const float* xb = x + (size_t)b * 256 * 4096;
  const unsigned short* wqrow = wq_bf + (size_t)(o0 + w * 16 + lr) * 256;

  f32x4 acc[8];
  f32x4 z = {0.f, 0.f, 0.f, 0.f};
#pragma unroll
  for (int i = 0; i < 8; ++i) acc[i] = z;
  float sacc = 0.f;

  for (int c0 = 0; c0 < 256; c0 += 32) {
    __syncthreads();
#pragma unroll
    for (int i = 0; i < 8; ++i) {
      int c = ch * 16 + i * 2;
      float v0 = xb[(size_t)(c0 + c) * 4096 + p0 + pl];
      float v1 = xb[(size_t)(c0 + c + 1) * 4096 + p0 + pl];
      sacc += v0 * v0 + v1 * v1;
      *(unsigned int*)&xnT[swz40(pl, c)] = pk2(v0 * g[c0 + c], v1 * g[c0 + c + 1]);
    }
    __syncthreads();
    short8 af = mk8(wqrow + c0 + lg * 8);
#pragma unroll
    for (int pt16 = 0; pt16 < 8; ++pt16) {
      short8 bf = mk8(&xnT[swz40(pt16 * 16 + lr, lg * 8)]);
      acc[pt16] = MFMA16(af, bf, acc[pt16]);
    }
  }

  sq[ch][pl] = sacc;
  __syncthreads();
  if (t < 128) rl[t] = rsqrtf((sq[0][t] + sq[1][t]) * (1.0f / 256.0f) + 1e-12f);
  __syncthreads();

  int obase = o0 + w * 16 + lg * 4;          // multiple of 4
  if (obase < 128) {
    // Q: [bh][p][d]
    int h = obase >> 5, d0 = obase & 31;
    unsigned short* dst = qbuf + ((size_t)(b * 4 + h) * 4096) * 32;
#pragma unroll
    for (int pt16 = 0; pt16 < 8; ++pt16) {
      int p = p0 + pt16 * 16 + lr;
      float rr = rl[pt16 * 16 + lr];
      unsigned int u0 = pk2(acc[pt16][0] * rr, acc[pt16][1] * rr);
      unsigned int u1 = pk2(acc[pt16][2] * rr, acc[pt16][3] * rr);
      uint2 uu = {u0, u1};
      *(uint2*)(dst + (size_t)p * 32 + d0) = uu;
    }
  } else if (obase < 256) {
    // K: fragment-linear. element (d, j): frag = d>>4, hi = (d>>3)&1, i = d&7
    int oh = obase - 128;
    int h = oh >> 5, d0 = oh & 31;           // d0..d0+3, d0 % 4 == 0
    int frag = d0 >> 4, hi = (d0 >> 3) & 1, i0 = d0 & 7;  // i0 in {0,4}
    unsigned short* dst = kbuf + (size_t)(b * 4 + h) * 131072
                         + frag * 512 + hi * 256 + i0;
#pragma unroll
    for (int pt16 = 0; pt16 < 8; ++pt16) {
      int jj = p0 + pt16 * 16 + lr;
      float rr = rl[pt16 * 16 + lr];
      int jtile = jj >> 5, j31 = jj & 31;
      unsigned int u0 = pk2(acc[pt16][0] * rr, acc[pt16][1] * rr);
      unsigned int u1 = pk2(acc[pt16][2] * rr, acc[pt16][3] * rr);
      uint2 uu = {u0, u1};
      *(uint2*)(dst + (size_t)jtile * 1024 + j31 * 8) = uu;
    }
  } else {
    // V: fragment-linear with sigma-stored j position.
    int oh = obase - 256;
    int h = oh >> 5, d0 = oh & 31;           // d0..d0+3 = lane d31 coordinate
    unsigned short* dst = vbuf + (size_t)(b * 4 + h) * 131072;
    // sigma: swap bits 2 and 3 of the within-16 index (involution)
    int sl = (lr & 3) | ((lr & 4) << 1) | ((lr & 8) >> 1);
#pragma unroll
    for (int pt16 = 0; pt16 < 8; ++pt16) {
      int jj = p0 + pt16 * 16 + sl;          // sigma-stored j position
      float rr = rl[pt16 * 16 + lr];
      int jtile = jj >> 5, j5 = jj & 31;
      int frag = j5 >> 4, hi = (j5 >> 3) & 1, i = j5 & 7;
      size_t base = (size_t)jtile * 1024 + frag * 512 + hi * 256 + i;
#pragma unroll
      for (int r = 0; r < 4; ++r)
        dst[base + (d0 + r) * 8] = f2bf(acc[pt16][r] * rr);
    }
  }
}

// ---------------- kernel 2: flash attention, coalesced fragment streams ----------------
// grid 2048 = 16 bh x 128 q-groups of 32 rows; 4 waves = 4 j-quarters.
// K/V fragment loads are lane-linear: 64 lanes x 16B = 1KB contiguous per load.
__device__ __forceinline__ void attn_tile(short8 kf0, short8 kf1, short8 vf0, short8 vf1,
                                          short8 qf0, short8 qf1,
                                          const f32x16& z16, float& m, float& ms,
                                          float& lsum, f32x16& oacc) {
  const float cexp = 0.25505654427102996f;  // 32^-0.5 * log2(e)
  f32x16 s = MFMA32(kf0, qf0, z16);
  s = MFMA32(kf1, qf1, s);

  // per-lane local max over 16 values (nested fmax -> v_max3)
  float a0 = fmaxf(fmaxf(s[0], s[1]), s[2]);
  float a1 = fmaxf(fmaxf(s[3], s[4]), s[5]);
  float a2 = fmaxf(fmaxf(s[6], s[7]), s[8]);
  float a3 = fmaxf(fmaxf(s[9], s[10]), s[11]);
  float a4 = fmaxf(fmaxf(s[12], s[13]), s[14]);
  float b0 = fmaxf(fmaxf(a0, a1), a2);
  float b1 = fmaxf(fmaxf(a3, a4), s[15]);
  float plmax = fmaxf(b0, b1);

  // defer-max: shared-ms update (with cross-half shuffle) only when needed.
  if (!__all(fmaf(plmax, cexp, -ms) <= 8.0f)) {
    float pmax = redmax32(plmax);           // keep ms identical across lane pair
    float mn = fmaxf(m, pmax);
    float fac = __builtin_amdgcn_exp2f((m - mn) * cexp);
    m = mn;
    ms = mn * cexp;
    lsum *= fac;
#pragma unroll
    for (int i = 0; i < 16; ++i) oacc[i] *= fac;
  }

  float p[16];
#pragma unroll
  for (int i = 0; i < 16; ++i) p[i] = __builtin_amdgcn_exp2f(fmaf(s[i], cexp, -ms));

  float s0 = ((p[0] + p[1]) + (p[2] + p[3])) + ((p[4] + p[5]) + (p[6] + p[7]));
  float s1 = ((p[8] + p[9]) + (p[10] + p[11])) + ((p[12] + p[13]) + (p[14] + p[15]));
  lsum += s0 + s1;

  // Own-lane B-fragments (fast RN pack); V stored sigma-permuted to match
  uint4v u0 = {pk2rn(p[0], p[1]), pk2rn(p[2], p[3]), pk2rn(p[4], p[5]), pk2rn(p[6], p[7])};
  uint4v u1 = {pk2rn(p[8], p[9]), pk2rn(p[10], p[11]), pk2rn(p[12], p[13]), pk2rn(p[14], p[15])};
  short8 pf0 = __builtin_bit_cast(short8, u0);
  short8 pf1 = __builtin_bit_cast(short8, u1);

  oacc = MFMA32(vf0, pf0, oacc);
  oacc = MFMA32(vf1, pf1, oacc);
}

__global__ __launch_bounds__(256, 4) void k_attn(const unsigned short* __restrict__ qbuf,
                                                 const unsigned short* __restrict__ kbuf,
                                                 const unsigned short* __restrict__ vbuf,
                                                 unsigned short* __restrict__ attno) {
  __shared__ float Ol[3][16][64];   // partner O partials (jq 1..3)
  __shared__ float Ml[3][2][64];    // partner m / lsum

  int bid = blockIdx.x;
  int wid = ((bid & 7) << 8) | (bid >> 3);   // XCD-contiguous (2048 % 8 == 0)
  int qg = wid & 127, bh = wid >> 7;
  int t = threadIdx.x, lane = t & 63, jq = t >> 6;
  int l31 = lane & 31, hi = lane >> 5;
  const float cexp = 0.25505654427102996f;

  const unsigned short* qgp = qbuf + (size_t)bh * 4096 * 32;
  const unsigned short* kt = kbuf + (size_t)bh * 131072;
  const unsigned short* vt = vbuf + (size_t)bh * 131072;

  int qrow = qg * 32 + l31;
  short8 qf0 = mk8(qgp + (size_t)qrow * 32 + hi * 8);
  short8 qf1 = mk8(qgp + (size_t)qrow * 32 + 16 + hi * 8);

  const f32x16 z16 = zero16();
  f32x16 oacc = zero16();
  float m = -1e30f, ms = -2.55e29f, lsum = 0.f;

  // lane-linear fragment streams: 1KB contiguous per load instruction
  const unsigned short* kp = kt + (size_t)(jq * 32) * 1024 + lane * 8;
  const unsigned short* vp = vt + (size_t)(jq * 32) * 1024 + lane * 8;

  short8 kf0a = mk8(kp), kf1a = mk8(kp + 512);
  short8 vf0a = mk8(vp), vf1a = mk8(vp + 512);
  kp += 1024;
  vp += 1024;
  short8 kf0b, kf1b, vf0b, vf1b;

  for (int it = 0; it < 16; ++it) {          // 16 iters x 2 tiles x 32 j = 1024 j
    kf0b = mk8(kp);
    kf1b = mk8(kp + 512);
    vf0b = mk8(vp);
    vf1b = mk8(vp + 512);
    kp += 1024;
    vp += 1024;
    attn_tile(kf0a, kf1a, vf0a, vf1a, qf0, qf1, z16, m, ms, lsum, oacc);

    kf0a = mk8(kp);                          // last iter: dead prefetch (mapped ws)
    kf1a = mk8(kp + 512);
    vf0a = mk8(vp);
    vf1a = mk8(vp + 512);
    kp += 1024;
    vp += 1024;
    attn_tile(kf0b, kf1b, vf0b, vf1b, qf0, qf1, z16, m, ms, lsum, oacc);
  }

  lsum = redsum32(lsum);   // pair row-total for this j-quarter

  if (jq > 0) {
#pragma unroll
    for (int i = 0; i < 16; ++i) Ol[jq - 1][i][lane] = oacc[i];
    Ml[jq - 1][0][lane] = m;
    Ml[jq - 1][1][lane] = lsum;
  }
  __syncthreads();
  if (jq == 0) {
    float m1 = Ml[0][0][lane], l1 = Ml[0][1][lane];
    float m2 = Ml[1][0][lane], l2 = Ml[1][1][lane];
    float m3 = Ml[2][0][lane], l3 = Ml[2][1][lane];
    float M = fmaxf(fmaxf(m, m1), fmaxf(m2, m3));
    float f0 = __builtin_amdgcn_exp2f((m - M) * cexp);
    float f1 = __builtin_amdgcn_exp2f((m1 - M) * cexp);
    float f2 = __builtin_amdgcn_exp2f((m2 - M) * cexp);
    float f3 = __builtin_amdgcn_exp2f((m3 - M) * cexp);
    float rinv = 1.0f / (lsum * f0 + l1 * f1 + l2 * f2 + l3 * f3);
    f0 *= rinv;
    f1 *= rinv;
    f2 *= rinv;
    f3 *= rinv;

    int b = bh >> 2, h = bh & 3;
    unsigned short* ob = attno + ((size_t)b * 4096 + qrow) * 128 + h * 32;
#pragma unroll
    for (int r2 = 0; r2 < 8; ++r2) {
      int reg = r2 * 2;
      int dv = (reg & 3) + 8 * (reg >> 2) + 4 * hi;
      float v0 = oacc[reg] * f0 + Ol[0][reg][lane] * f1 + Ol[1][reg][lane] * f2 + Ol[2][reg][lane] * f3;
      float v1 = oacc[reg + 1] * f0 + Ol[0][reg + 1][lane] * f1 + Ol[1][reg + 1][lane] * f2 + Ol[2][reg + 1][lane] * f3;
      *(unsigned int*)(ob + dv) = pk2(v0, v1);
    }
  }
}

// ---------------- kernel 3: output projection + bias ----------------
__global__ __launch_bounds__(256) void k_out(const unsigned short* __restrict__ attno,
                                             const unsigned short* __restrict__ wo_bf,
                                             const float* __restrict__ bo,
                                             float* __restrict__ out) {
  int bid = blockIdx.x;
  int b = bid >> 6;
  int p0 = (bid & 63) * 64;
  int t = threadIdx.x, lane = t & 63, w = t >> 6;
  int lr = lane & 15, lg = lane >> 4;

  f32x4 z = {0.f, 0.f, 0.f, 0.f};
  f32x4 acc[4][4];
#pragma unroll
  for (int i = 0; i < 4; ++i)
#pragma unroll
    for (int j = 0; j < 4; ++j) acc[i][j] = z;

  for (int c0 = 0; c0 < 128; c0 += 32) {
    short8 bfr[4];
#pragma unroll
    for (int pt16 = 0; pt16 < 4; ++pt16)
      bfr[pt16] = mk8(attno + (size_t)(b * 4096 + p0 + pt16 * 16 + lr) * 128 + c0 + lg * 8);
#pragma unroll
    for (int ct = 0; ct < 4; ++ct) {
      short8 afr = mk8(wo_bf + (size_t)(w * 64 + ct * 16 + lr) * 128 + c0 + lg * 8);
#pragma unroll
      for (int pt16 = 0; pt16 < 4; ++pt16)
        acc[ct][pt16] = MFMA16(afr, bfr[pt16], acc[ct][pt16]);
    }
  }

#pragma unroll
  for (int ct = 0; ct < 4; ++ct) {
#pragma unroll
    for (int pt16 = 0; pt16 < 4; ++pt16) {
#pragma unroll
      for (int r = 0; r < 4; ++r) {
        int co = w * 64 + ct * 16 + lg * 4 + r;
        int p = p0 + pt16 * 16 + lr;
        out[((size_t)b * 256 + co) * 4096 + p] = acc[ct][pt16][r] + bo[co];
      }
    }
  }
}

extern "C" void kernel_launch(void* const* d_in, const int* in_sizes, int n_in,
                              void* d_out, int out_size, void* d_ws, size_t ws_size,
                              hipStream_t stream) {
  const float* x = (const float*)d_in[0];
  const float* g = (const float*)d_in[1];
  const float* wq = (const float*)d_in[2];
  const float* wo = (const float*)d_in[3];
  const float* bo = (const float*)d_in[4];
  float* out = (float*)d_out;

  char* ws = (char*)d_ws;
  unsigned short* wq_bf = (unsigned short*)(ws + 65536);     // 196608 B
  unsigned short* wo_bf = (unsigned short*)(ws + 262144);    // 65536 B
  unsigned short* qbuf = (unsigned short*)(ws + 327680);     // 4 MiB
  unsigned short* kbuf = (unsigned short*)(ws + 4521984);    // 4 MiB
  unsigned short* vbuf = (unsigned short*)(ws + 8716288);    // 4 MiB
  unsigned short* attno = (unsigned short*)(ws + 12910592);  // 4 MiB

  k_prep<<<dim3(384), dim3(256), 0, stream>>>(wq, wo, wq_bf, wo_bf);
  k_qkv<<<dim3(768), dim3(256), 0, stream>>>(x, g, wq_bf, qbuf, kbuf, vbuf);
  k_attn<<<dim3(2048), dim3(256), 0, stream>>>(qbuf, kbuf, vbuf, attno);
  k_out<<<dim3(256), dim3(256), 0, stream>>>(attno, wo_bf, bo, out);
}